// Round 3
// baseline (689.330 us; speedup 1.0000x reference)
//
#include <hip/hip_runtime.h>

// NeighborSample: x[8,64,64,192] f32 -> out[8*64*64, 5, 5, 192] f32
//
// R7: FILL-MIMIC probe. Ledger so far (all ~630 us total, kernel ~230 us):
//   R0-R3 gather (block-chunked writes)            ~2.6 TB/s eff
//   R4 scatter (25 streams/wave)                    226 us
//   R5 LDS-staged, per-block linear 307KB chunks    229 us
//   R6 R5 + XCD swizzle + nontemporal stores        232 us
// Meanwhile the harness's fillBufferAligned writes 2.5 GB at 6.2 TB/s on
// this same buffer at 10% occupancy. Write ordering within a block, XCD
// locality, and the L2 write path are all measured-irrelevant. The ONE
// remaining structural difference: the fill is a device-wide GRID-STRIDE
// sliding window (instantaneous store addresses span one contiguous ~MB
// window sweeping the buffer = one DRAM stream), while all our kernels were
// block-chunked (hundreds of concurrent private write streams over 629 MB).
//
// This kernel reproduces the fill's access pattern exactly: grid-stride
// over the flat f4 output index, 1024x256 threads, stride = 4 MB window,
// 150 exact iterations per thread. Source index is derived from the flat
// output index j by constant divisions (j -> pixel p, tap, k4 -> padded
// gather); input is 24 MB = L3-resident, so the 629 MB of re-reads are L3
// hits and HBM sees a pure fill-shaped write stream.
//
// Predict: kernel ~110-140 us -> dur ~515-545 if the stream-shape theory
// holds; if unchanged, the kernel is at its effective roofline.

typedef float f32x4 __attribute__((ext_vector_type(4)));

constexpr int B = 8;
constexpr int H = 64;
constexpr int W = 64;
constexpr int C4 = 48;                 // 192 ch / 4
constexpr int K = 5;
constexpr int PAD = K / 2;
constexpr int ROW = K * K * C4;        // 1200 f4 per output pixel

constexpr unsigned NPIX  = (unsigned)B * H * W;      // 32768
constexpr unsigned TOTF4 = NPIX * ROW;               // 39,321,600
constexpr int BLOCK = 256;
constexpr unsigned GRID = 1024;                      // 4 blocks/CU, no LDS
constexpr unsigned STRIDE = GRID * BLOCK;            // 262,144 (= 4 MB window)
constexpr int ITERS = (int)(TOTF4 / STRIDE);         // exactly 150

__global__ __launch_bounds__(BLOCK) void neighbor_fillorder_kernel(
    const f32x4* __restrict__ in, f32x4* __restrict__ out) {
  unsigned j = blockIdx.x * BLOCK + threadIdx.x;   // flat f4 output index

#pragma unroll 5
  for (int it = 0; it < ITERS; ++it, j += STRIDE) {
    // j = p*1200 + tap*48 + k4 ; tap = oi*5 + oj
    unsigned p   = j / 1200u;                  // magic-mul
    unsigned r   = j - p * 1200u;
    unsigned tap = r / 48u;
    unsigned k4  = r - tap * 48u;
    unsigned oi  = tap / 5u;
    unsigned oj  = tap - oi * 5u;

    int x = (int)(p & (W - 1));
    int y = (int)((p >> 6) & (H - 1));
    int b = (int)(p >> 12);
    int sy = y + (int)oi - PAD;
    int sx = x + (int)oj - PAD;

    f32x4 v = {0.f, 0.f, 0.f, 0.f};
    if ((unsigned)sy < (unsigned)H && (unsigned)sx < (unsigned)W)
      v = in[((unsigned)(b * H + sy) * W + (unsigned)sx) * C4 + k4];

    out[j] = v;   // device-wide sliding-window sweep, fill-identical shape
  }
}

extern "C" void kernel_launch(void* const* d_in, const int* in_sizes, int n_in,
                              void* d_out, int out_size, void* d_ws, size_t ws_size,
                              hipStream_t stream) {
  const f32x4* in = (const f32x4*)d_in[0];
  f32x4* out = (f32x4*)d_out;
  neighbor_fillorder_kernel<<<GRID, BLOCK, 0, stream>>>(in, out);
}

// Round 4
// 627.303 us; speedup vs baseline: 1.0989x; 1.0989x over previous
//
#include <hip/hip_runtime.h>

// NeighborSample: x[8,64,64,192] f32 -> out[8*64*64, 5, 5, 192] f32
//
// R8: restore the measured-best R4 SCATTER formulation (629.6 us) + nt
// stores. Session ledger:
//   R4 scatter (this structure)                 631.3 us  <- best
//   R5 LDS-staged, linear per-block writes      634.2 us
//   R6 R5 + XCD-bijective swizzle + nt stores   636.8 us
//   R7 grid-stride fill-order gather            689.3 us  (regression)
// R7's +55 us proves dur_us is sensitive to real kernel slowdowns; the
// <1% spread of R4-R6 across radically different store orderings therefore
// means the kernel portion is already at its floor (~110-140 us for 654 MB
// ~= 5-6 TB/s effective, at the achievable write ceiling). The remaining
// ~500 us of dur_us is the harness reset: a 2.46 GB poison fill (405 us at
// 6.2 TB/s, itself roofline) + dozens of small restore dispatches.
//
// One thread owns one input float4 (24 MB read once, coalesced) and stores
// it to the 25 output taps it feeds; all 25 offsets are compile-time
// constants off pbase. Border threads zero-fill their own OOB taps, so
// every output element is written exactly once. Interior waves (88%) take a
// predicate-free path. Stores are nontemporal: output is write-once, never
// re-read; keep the 25 write streams out of the 4 MB per-XCD L2.

typedef float f32x4 __attribute__((ext_vector_type(4)));

constexpr int B = 8;
constexpr int H = 64;
constexpr int W = 64;
constexpr int C4 = 48;              // 192 ch / 4 = float4 per channel row
constexpr int K = 5;
constexpr int PAD = K / 2;
constexpr int ROW = K * K * C4;     // 1200 float4 per output pixel

constexpr unsigned NPIX  = (unsigned)B * H * W;   // 32768
constexpr unsigned TOTAL = NPIX * C4;             // 1,572,864 threads
constexpr int BLOCK = 256;
constexpr unsigned GRID = TOTAL / BLOCK;          // 6144, exact

__global__ __launch_bounds__(BLOCK) void neighbor_scatter_kernel(
    const f32x4* __restrict__ in, f32x4* __restrict__ out) {
  unsigned g  = blockIdx.x * BLOCK + threadIdx.x;  // p*48 + k4
  unsigned k4 = g % C4;                            // magic-mul
  unsigned p  = g / C4;

  int xx = (int)(p & (W - 1));
  int yy = (int)((p >> 6) & (H - 1));

  f32x4 v = in[g];                                 // coalesced, read once
  int pbase = (int)(p * (unsigned)ROW + k4);

  bool interior = (yy >= PAD) & (yy < H - PAD) & (xx >= PAD) & (xx < W - PAD);

  if (__all(interior)) {
    // All 25 targets valid; offsets are compile-time constants.
#pragma unroll
    for (int oi = 0; oi < K; ++oi)
#pragma unroll
      for (int oj = 0; oj < K; ++oj) {
        const int off = ((PAD - oi) * W + (PAD - oj)) * ROW + (oi * K + oj) * C4;
        __builtin_nontemporal_store(v, &out[pbase + off]);
      }
  } else {
    const f32x4 z = {0.f, 0.f, 0.f, 0.f};
#pragma unroll
    for (int oi = 0; oi < K; ++oi)
#pragma unroll
      for (int oj = 0; oj < K; ++oj) {
        const int off = ((PAD - oi) * W + (PAD - oj)) * ROW + (oi * K + oj) * C4;
        // Scatter: value v lands at tap (oi,oj) of pixel (yy+2-oi, xx+2-oj)
        int ty = yy + PAD - oi, tx = xx + PAD - oj;
        if ((unsigned)ty < (unsigned)H && (unsigned)tx < (unsigned)W)
          __builtin_nontemporal_store(v, &out[pbase + off]);
        // Zero-fill: own pixel's tap (oi,oj) reads OOB source -> must be 0
        int sy = yy + oi - PAD, sx = xx + oj - PAD;
        if (!((unsigned)sy < (unsigned)H && (unsigned)sx < (unsigned)W))
          __builtin_nontemporal_store(z, &out[pbase + (oi * K + oj) * C4]);
      }
  }
}

extern "C" void kernel_launch(void* const* d_in, const int* in_sizes, int n_in,
                              void* d_out, int out_size, void* d_ws, size_t ws_size,
                              hipStream_t stream) {
  const f32x4* in = (const f32x4*)d_in[0];
  f32x4* out = (f32x4*)d_out;
  neighbor_scatter_kernel<<<GRID, BLOCK, 0, stream>>>(in, out);
}